// Round 3
// baseline (10682.506 us; speedup 1.0000x reference)
//
#include <hip/hip_runtime.h>
#include <hip/hip_bf16.h>

#define N_NODES 50000
#define N_ENV   1000000
#define N_EDGES 200000

// tanh(x) = (e^{2x}-1)/(e^{2x}+1); clamp so exp never overflows
__device__ __forceinline__ float fast_tanh(float x){
  float xc = fminf(fmaxf(x, -10.f), 10.f);
  float t  = __expf(2.f * xc);
  return __fdividef(t - 1.f, t + 1.f);
}

__global__ void k_zero(float* __restrict__ p, int n){
  int i = blockIdx.x * blockDim.x + threadIdx.x;
  int stride = gridDim.x * blockDim.x;
  for (; i < n; i += stride) p[i] = 0.f;
}

__global__ __launch_bounds__(256) void k_env(
    const float* __restrict__ env_vec, const float* __restrict__ atom_attr,
    const int*  __restrict__ env_index,
    const float* __restrict__ W1, const float* __restrict__ B1,
    const float* __restrict__ W2, const float* __restrict__ B2,
    const float* __restrict__ W3, const float* __restrict__ B3,
    float* __restrict__ sums, float* __restrict__ cnt)
{
  // Transposed weights in LDS: contiguous along the reduction dim so the
  // wave-uniform inner-loop reads merge into broadcast ds_read_b128.
  __shared__ float sW1[32*9];    // sW1[j*9+i]  = W1[i*32+j]
  __shared__ float sW2[64*32];   // sW2[j*32+i] = W2[i*64+j]
  __shared__ float sW3[64*64];   // sW3[j*64+i] = W3[i*64+j]
  __shared__ float sB1[32], sB2[64], sB3[64];
  for (int k = threadIdx.x; k < 32*9;  k += 256){ int j = k/9,  i = k%9;  sW1[k] = W1[i*32+j]; }
  for (int k = threadIdx.x; k < 64*32; k += 256){ int j = k>>5, i = k&31; sW2[k] = W2[i*64+j]; }
  for (int k = threadIdx.x; k < 64*64; k += 256){ int j = k>>6, i = k&63; sW3[k] = W3[i*64+j]; }
  if (threadIdx.x < 32) sB1[threadIdx.x] = B1[threadIdx.x];
  if (threadIdx.x < 64) sB2[threadIdx.x] = B2[threadIdx.x];
  if (threadIdx.x < 64) sB3[threadIdx.x] = B3[threadIdx.x];
  __syncthreads();

  int e = blockIdx.x * 256 + threadIdx.x;
  if (e >= N_ENV) return;

  float v0 = env_vec[3*e+0];
  float v1 = env_vec[3*e+1];
  float v2 = env_vec[3*e+2];
  float r = sqrtf(v0*v0 + v1*v1 + v2*v2);
  float invr = 1.f / r;
  float xx = (r - 6.f) * (-1.f/3.f);                 // (r-RC)/(RS-RC)
  float mid = invr * (xx*xx*xx*(10.f + xx*(-15.f + 6.f*xx)) + 1.f);
  float snorm = (r < 3.f) ? invr : ((r < 6.f) ? mid : 0.f);

  int src = env_index[e];
  int dst = env_index[N_ENV + e];

  float x[9];
  x[0] = snorm;
  float4 sa = *reinterpret_cast<const float4*>(atom_attr + src*4);
  float4 da = *reinterpret_cast<const float4*>(atom_attr + dst*4);
  x[1]=sa.x; x[2]=sa.y; x[3]=sa.z; x[4]=sa.w;
  x[5]=da.x; x[6]=da.y; x[7]=da.z; x[8]=da.w;

  float h1[32];
  #pragma unroll
  for (int j = 0; j < 32; j++){
    float acc = sB1[j];
    #pragma unroll
    for (int i = 0; i < 9; i++) acc += x[i] * sW1[j*9 + i];
    h1[j] = fast_tanh(acc);
  }

  float h2[64];
  #pragma unroll
  for (int j = 0; j < 64; j++){
    float acc = sB2[j];
    #pragma unroll
    for (int i = 0; i < 32; i++) acc += h1[i] * sW2[j*32 + i];
    h2[j] = fast_tanh(acc);
  }

  float* srow = sums + (size_t)dst * 192;
  #pragma unroll
  for (int d = 0; d < 64; d++){
    float acc = sB3[d];
    #pragma unroll
    for (int i = 0; i < 64; i++) acc += h2[i] * sW3[d*64 + i];
    float hd = fast_tanh(acc) + h2[d];
    atomicAdd(srow + d*3 + 0, hd * v0);
    atomicAdd(srow + d*3 + 1, hd * v1);
    atomicAdd(srow + d*3 + 2, hd * v2);
  }
  atomicAdd(cnt + dst, 1.f);
}

// 4 nodes per 256-thread block; 64 threads per node, thread d computes desc[d][0..7]
__global__ __launch_bounds__(256) void k_node(
    const float* __restrict__ sums, const float* __restrict__ cnt,
    float* __restrict__ node_out)
{
  int t = threadIdx.x;
  int node = blockIdx.x * 4 + (t >> 6);
  int d = t & 63;
  const float* srow = sums + (size_t)node * 192;
  float inv = 1.f / fmaxf(cnt[node], 1.f);
  float ad0 = srow[d*3+0] * inv;
  float ad1 = srow[d*3+1] * inv;
  float ad2 = srow[d*3+2] * inv;
  float o[8];
  #pragma unroll
  for (int e2 = 0; e2 < 8; e2++){
    float ae0 = srow[e2*3+0] * inv;
    float ae1 = srow[e2*3+1] * inv;
    float ae2 = srow[e2*3+2] * inv;
    o[e2] = ad0*ae0 + ad1*ae1 + ad2*ae2;
  }
  float* dst = node_out + (size_t)node * 512 + d * 8;
  *reinterpret_cast<float4*>(dst)     = make_float4(o[0], o[1], o[2], o[3]);
  *reinterpret_cast<float4*>(dst + 4) = make_float4(o[4], o[5], o[6], o[7]);
}

// 2 edges per 256-thread block; 128 threads per edge, one float4 (16B) per thread
__global__ __launch_bounds__(256) void k_edge(
    const float* __restrict__ node_out, const int* __restrict__ edge_index,
    float* __restrict__ edge_out)
{
  int t = threadIdx.x;
  int e = blockIdx.x * 2 + (t >> 7);
  int l = t & 127;
  int s  = edge_index[e];
  int dn = edge_index[N_EDGES + e];
  const float4* rs = reinterpret_cast<const float4*>(node_out + (size_t)s  * 512);
  const float4* rd = reinterpret_cast<const float4*>(node_out + (size_t)dn * 512);
  float4 a = rs[l];
  float4 b = rd[l];
  float4 o = make_float4(a.x + b.x, a.y + b.y, a.z + b.z, a.w + b.w);
  reinterpret_cast<float4*>(edge_out + (size_t)e * 512)[l] = o;
}

extern "C" void kernel_launch(void* const* d_in, const int* in_sizes, int n_in,
                              void* d_out, int out_size, void* d_ws, size_t ws_size,
                              hipStream_t stream) {
  const float* env_vec    = (const float*)d_in[0];
  const float* atom_attr  = (const float*)d_in[1];
  const int*   env_index  = (const int*)  d_in[2];
  const int*   edge_index = (const int*)  d_in[3];
  const float* W1 = (const float*)d_in[4];
  const float* B1 = (const float*)d_in[5];
  const float* W2 = (const float*)d_in[6];
  const float* B2 = (const float*)d_in[7];
  const float* W3 = (const float*)d_in[8];
  const float* B3 = (const float*)d_in[9];

  float* out      = (float*)d_out;
  float* node_out = out;                               // 50000*512
  float* edge_out = out + (size_t)N_NODES * 512;       // 200000*512

  float* sums = (float*)d_ws;                          // [N_NODES*192]
  float* cnt  = sums + (size_t)N_NODES * 192;          // [N_NODES]

  int nzero = N_NODES * 193;
  k_zero<<<2048, 256, 0, stream>>>(sums, nzero);

  k_env<<<(N_ENV + 255) / 256, 256, 0, stream>>>(
      env_vec, atom_attr, env_index, W1, B1, W2, B2, W3, B3, sums, cnt);

  k_node<<<N_NODES / 4, 256, 0, stream>>>(sums, cnt, node_out);

  k_edge<<<N_EDGES / 2, 256, 0, stream>>>(node_out, edge_index, edge_out);
}